// Round 7
// baseline (168.839 us; speedup 1.0000x reference)
//
#include <hip/hip_runtime.h>

#define D0 232
#define MED 1024
#define HID 256
#define TDIM 768
#define NTRAIN 4096

typedef short bf16x8 __attribute__((ext_vector_type(8)));
typedef float f32x4  __attribute__((ext_vector_type(4)));
typedef unsigned short u16;

__device__ __forceinline__ u16 f2bf(float f) {
    unsigned u = __float_as_uint(f);
    return (u16)((u + 0x7FFFu + ((u >> 16) & 1u)) >> 16);
}
__device__ __forceinline__ float bf2f(u16 h) {
    return __uint_as_float(((unsigned)h) << 16);
}
__device__ __forceinline__ void cvt8(const float4& a0, const float4& a1,
                                     bf16x8& h, bf16x8& l) {
    float f[8] = {a0.x, a0.y, a0.z, a0.w, a1.x, a1.y, a1.z, a1.w};
    #pragma unroll
    for (int i = 0; i < 8; ++i) {
        u16 hh = f2bf(f[i]);
        h[i] = (short)hh;
        l[i] = (short)f2bf(f[i] - bf2f(hh));
    }
}
__device__ __forceinline__ void cvt4(const float4 v, ushort4& h, ushort4& l) {
    h.x = f2bf(v.x); l.x = f2bf(v.x - bf2f(h.x));
    h.y = f2bf(v.y); l.y = f2bf(v.y - bf2f(h.y));
    h.z = f2bf(v.z); l.z = f2bf(v.z - bf2f(h.z));
    h.w = f2bf(v.w); l.w = f2bf(v.w - bf2f(h.w));
}

// XOR row swizzle for A-LDS: both ds_write_b128 and ds_read_b128 become
// conflict-free (2-way over 32 banks, which is free).
#define SROW(r, k) ((((r) ^ (k)) & 7) | ((r) & ~7))

// ---------------- node GEMM: C = A1@B1^T [+ A2@B2^T] + bias ----------------
// A in LDS (8 KB, shared by 4 waves); B fragments straight from L2 (W planes
// are tiny + L2-resident). Tile 32x64, 4 waves each 32x16 output. Split-bf16
// 3-term MFMA. CONVA: A1 is fp32, split during staging (x0 GEMM only).
template<int CONVA, int RELU, int EMIT, int NPASS>
__global__ __launch_bounds__(256, 2) void gemm_node(
    const float* __restrict__ A1f,
    const short* __restrict__ A1h, const short* __restrict__ A1l,
    const short* __restrict__ B1h, const short* __restrict__ B1l,
    const short* __restrict__ A2h, const short* __restrict__ A2l,
    const short* __restrict__ B2h, const short* __restrict__ B2l,
    const float* __restrict__ bias,
    float* __restrict__ Cf, u16* __restrict__ Chi, u16* __restrict__ Clo,
    int M, int N, int K)
{
    constexpr int TBM = 32;
    __shared__ short sAh[8 * TBM * 8], sAl[8 * TBM * 8];

    const int tid  = threadIdx.x;
    const int lane = tid & 63;
    const int wn   = tid >> 6;        // wave 0..3 along N
    const int l15  = lane & 15;
    const int l4   = lane >> 4;
    const int row0 = blockIdx.y * TBM;
    const int col0 = blockIdx.x * 64;

    const int aRow  = tid >> 3;       // 0..31
    const int aKc   = tid & 7;
    const int aSlot = (aKc * TBM + SROW(aRow, aKc)) * 8;

    const int  colW  = col0 + wn * 16 + l15;
    const bool colOk = colW < N;
    const size_t wBase = (size_t)(colOk ? colW : 0) * K;

    const bf16x8 Z8 = {0, 0, 0, 0, 0, 0, 0, 0};
    f32x4 acc[2];
    acc[0] = (f32x4){0.f, 0.f, 0.f, 0.f};
    acc[1] = (f32x4){0.f, 0.f, 0.f, 0.f};

    for (int pass = 0; pass < NPASS; ++pass) {
        const short* Bh = pass ? B2h : B1h;
        const short* Bl = pass ? B2l : B1l;
        const short* Ah = pass ? A2h : A1h;
        const short* Al = pass ? A2l : A1l;
        const size_t aOff = (size_t)(row0 + aRow) * K;

        float4 qa0, qa1;
        bf16x8 ph, pl;

        auto loadA = [&](int k0) {
            int gk = k0 + aKc * 8;
            bool v = gk < K;
            if (CONVA && pass == 0) {
                qa0 = v ? *(const float4*)(A1f + aOff + gk)     : make_float4(0.f,0.f,0.f,0.f);
                qa1 = v ? *(const float4*)(A1f + aOff + gk + 4) : make_float4(0.f,0.f,0.f,0.f);
            } else {
                ph = v ? *(const bf16x8*)(Ah + aOff + gk) : Z8;
                pl = v ? *(const bf16x8*)(Al + aOff + gk) : Z8;
            }
        };

        loadA(0);
        for (int k0 = 0; k0 < K; k0 += 64) {
            // B fragments for this K-step, straight from global (L2)
            bf16x8 bh[2], bl[2];
            #pragma unroll
            for (int ks = 0; ks < 2; ++ks) {
                int kb = k0 + (ks * 4 + l4) * 8;
                bool v = colOk && kb < K;
                bh[ks] = v ? *(const bf16x8*)(Bh + wBase + kb) : Z8;
                bl[ks] = v ? *(const bf16x8*)(Bl + wBase + kb) : Z8;
            }
            // stage A
            if (CONVA && pass == 0) {
                bf16x8 h, l; cvt8(qa0, qa1, h, l);
                *(bf16x8*)(sAh + aSlot) = h;
                *(bf16x8*)(sAl + aSlot) = l;
            } else {
                *(bf16x8*)(sAh + aSlot) = ph;
                *(bf16x8*)(sAl + aSlot) = pl;
            }
            __syncthreads();
            if (k0 + 64 < K) loadA(k0 + 64);   // prefetch next A tile

            #pragma unroll
            for (int ks = 0; ks < 2; ++ks) {
                const int pb = ks * 4 + l4;
                bf16x8 ah[2], al[2];
                #pragma unroll
                for (int m = 0; m < 2; ++m) {
                    int sl = (pb * TBM + SROW(m * 16 + l15, pb)) * 8;
                    ah[m] = *(const bf16x8*)(sAh + sl);
                    al[m] = *(const bf16x8*)(sAl + sl);
                }
                #pragma unroll
                for (int m = 0; m < 2; ++m)
                    acc[m] = __builtin_amdgcn_mfma_f32_16x16x32_bf16(ah[m], bh[ks], acc[m], 0, 0, 0);
                #pragma unroll
                for (int m = 0; m < 2; ++m)
                    acc[m] = __builtin_amdgcn_mfma_f32_16x16x32_bf16(ah[m], bl[ks], acc[m], 0, 0, 0);
                #pragma unroll
                for (int m = 0; m < 2; ++m)
                    acc[m] = __builtin_amdgcn_mfma_f32_16x16x32_bf16(al[m], bh[ks], acc[m], 0, 0, 0);
            }
            __syncthreads();
        }
    }

    if (colOk) {
        const float bv = bias[colW];
        #pragma unroll
        for (int m = 0; m < 2; ++m) {
            #pragma unroll
            for (int r = 0; r < 4; ++r) {
                int row = row0 + m * 16 + l4 * 4 + r;
                float v = acc[m][r] + bv;
                if (RELU) v = fmaxf(v, 0.0f);
                size_t idx = (size_t)row * N + colW;
                Cf[idx] = v;
                if (EMIT) {
                    u16 h = f2bf(v);
                    Chi[idx] = h;
                    Clo[idx] = f2bf(v - bf2f(h));
                }
            }
        }
    }
}

// ------- fused q-GEMM + head -------
// out[i] = ((Q[pid[i]]@Wt^T + b) * x2[mid[i]]) @ clsW^T + cls_b
// Tile 64x256 (4 waves, wave 64x64), A in LDS (16 KB), B in registers from L2.
__global__ __launch_bounds__(256) void gemm_q_head(
    const float* __restrict__ Q, const int* __restrict__ prompt_ids,
    const short* __restrict__ Wh, const short* __restrict__ Wl,
    const float* __restrict__ bias,
    const float* __restrict__ x2f, const int* __restrict__ model_ids,
    const float* __restrict__ cls_W, const float* __restrict__ cls_b,
    float* __restrict__ out)
{
    constexpr int TBM = 64, K = TDIM, N = D0;
    __shared__ short sAh[8 * TBM * 8], sAl[8 * TBM * 8];
    __shared__ float hacc[TBM][2];

    const int tid  = threadIdx.x;
    const int lane = tid & 63;
    const int wn   = tid >> 6;        // wave 0..3: cols wn*64..wn*64+63
    const int l15  = lane & 15;
    const int l4   = lane >> 4;
    const int row0 = blockIdx.x * TBM;

    const int cid0 = tid * 2, cid1 = tid * 2 + 1;
    const int r0 = cid0 >> 3, kc0 = cid0 & 7;
    const int r1 = cid1 >> 3, kc1 = cid1 & 7;
    const int slot0 = (kc0 * TBM + SROW(r0, kc0)) * 8;
    const int slot1 = (kc1 * TBM + SROW(r1, kc1)) * 8;
    const size_t ab0 = (size_t)prompt_ids[row0 + r0] * K;
    const size_t ab1 = (size_t)prompt_ids[row0 + r1] * K;

    int colW[4]; bool cOk[4]; size_t wB[4];
    #pragma unroll
    for (int j = 0; j < 4; ++j) {
        colW[j] = wn * 64 + j * 16 + l15;
        cOk[j]  = colW[j] < N;
        wB[j]   = (size_t)(cOk[j] ? colW[j] : 0) * K;
    }

    const bf16x8 Z8 = {0, 0, 0, 0, 0, 0, 0, 0};
    f32x4 acc[4][4];
    #pragma unroll
    for (int m = 0; m < 4; ++m)
        #pragma unroll
        for (int j = 0; j < 4; ++j)
            acc[m][j] = (f32x4){0.f, 0.f, 0.f, 0.f};

    float4 qa0, qa1, qa2, qa3;
    auto loadA = [&](int k0) {
        qa0 = *(const float4*)(Q + ab0 + k0 + kc0 * 8);
        qa1 = *(const float4*)(Q + ab0 + k0 + kc0 * 8 + 4);
        qa2 = *(const float4*)(Q + ab1 + k0 + kc1 * 8);
        qa3 = *(const float4*)(Q + ab1 + k0 + kc1 * 8 + 4);
    };

    loadA(0);
    for (int k0 = 0; k0 < K; k0 += 64) {
        // B fragments for both ks sub-steps, straight from L2
        bf16x8 bh[2][4], bl[2][4];
        #pragma unroll
        for (int ks = 0; ks < 2; ++ks) {
            int kb = k0 + (ks * 4 + l4) * 8;
            #pragma unroll
            for (int j = 0; j < 4; ++j) {
                bh[ks][j] = cOk[j] ? *(const bf16x8*)(Wh + wB[j] + kb) : Z8;
                bl[ks][j] = cOk[j] ? *(const bf16x8*)(Wl + wB[j] + kb) : Z8;
            }
        }
        // stage A (fp32 -> hi/lo)
        {
            bf16x8 h, l;
            cvt8(qa0, qa1, h, l);
            *(bf16x8*)(sAh + slot0) = h; *(bf16x8*)(sAl + slot0) = l;
            cvt8(qa2, qa3, h, l);
            *(bf16x8*)(sAh + slot1) = h; *(bf16x8*)(sAl + slot1) = l;
        }
        __syncthreads();
        if (k0 + 64 < K) loadA(k0 + 64);

        #pragma unroll
        for (int ks = 0; ks < 2; ++ks) {
            const int pb = ks * 4 + l4;
            bf16x8 ah[4], al[4];
            #pragma unroll
            for (int m = 0; m < 4; ++m) {
                int sl = (pb * TBM + SROW(m * 16 + l15, pb)) * 8;
                ah[m] = *(const bf16x8*)(sAh + sl);
                al[m] = *(const bf16x8*)(sAl + sl);
            }
            #pragma unroll
            for (int m = 0; m < 4; ++m)
                #pragma unroll
                for (int j = 0; j < 4; ++j)
                    acc[m][j] = __builtin_amdgcn_mfma_f32_16x16x32_bf16(ah[m], bh[ks][j], acc[m][j], 0, 0, 0);
            #pragma unroll
            for (int m = 0; m < 4; ++m)
                #pragma unroll
                for (int j = 0; j < 4; ++j)
                    acc[m][j] = __builtin_amdgcn_mfma_f32_16x16x32_bf16(ah[m], bl[ks][j], acc[m][j], 0, 0, 0);
            #pragma unroll
            for (int m = 0; m < 4; ++m)
                #pragma unroll
                for (int j = 0; j < 4; ++j)
                    acc[m][j] = __builtin_amdgcn_mfma_f32_16x16x32_bf16(al[m], bh[ks][j], acc[m][j], 0, 0, 0);
        }
        __syncthreads();
    }

    // ---- fused head ----
    if (tid < TBM * 2) ((float*)hacc)[tid] = 0.f;
    __syncthreads();

    float bv[4], w0[4], w1[4];
    #pragma unroll
    for (int j = 0; j < 4; ++j) {
        bv[j] = cOk[j] ? bias[colW[j]]      : 0.f;
        w0[j] = cOk[j] ? cls_W[colW[j]]     : 0.f;
        w1[j] = cOk[j] ? cls_W[N + colW[j]] : 0.f;
    }

    float s0[4][4] = {}, s1[4][4] = {};
    #pragma unroll
    for (int m = 0; m < 4; ++m) {
        #pragma unroll
        for (int rr = 0; rr < 4; ++rr) {
            const int mid = model_ids[row0 + m * 16 + l4 * 4 + rr];
            const float* xr = x2f + (size_t)mid * N;
            #pragma unroll
            for (int j = 0; j < 4; ++j) {
                if (cOk[j]) {
                    float pv = (acc[m][j][rr] + bv[j]) * xr[colW[j]];
                    s0[m][rr] += pv * w0[j];
                    s1[m][rr] += pv * w1[j];
                }
            }
        }
    }
    #pragma unroll
    for (int off = 1; off < 16; off <<= 1)
        #pragma unroll
        for (int m = 0; m < 4; ++m)
            #pragma unroll
            for (int rr = 0; rr < 4; ++rr) {
                s0[m][rr] += __shfl_xor(s0[m][rr], off);
                s1[m][rr] += __shfl_xor(s1[m][rr], off);
            }
    if (l15 == 0) {
        #pragma unroll
        for (int m = 0; m < 4; ++m)
            #pragma unroll
            for (int rr = 0; rr < 4; ++rr) {
                int lr = m * 16 + l4 * 4 + rr;
                atomicAdd(&hacc[lr][0], s0[m][rr]);
                atomicAdd(&hacc[lr][1], s1[m][rr]);
            }
    }
    __syncthreads();
    if (tid < TBM * 2) {
        int r = tid >> 1, c = tid & 1;
        out[(size_t)(row0 + r) * 2 + c] = hacc[r][c] + cls_b[c];
    }
}

// ---------------- fused histogram + weight-plane conversion ----------------
struct Seg  { const float* src; u16* hi; u16* lo; int n4; };
struct Segs { Seg s[6]; };

__global__ __launch_bounds__(256) void hist_conv(
    const int* __restrict__ dst, int* __restrict__ hist, int E, int HB,
    Segs segs, int total4)
{
    if ((int)blockIdx.x < HB) {
        int e = blockIdx.x * 256 + threadIdx.x;
        if (e < E) atomicAdd(&hist[dst[e]], 1);
    } else {
        int i = (blockIdx.x - HB) * 256 + threadIdx.x;
        const int stride = (gridDim.x - HB) * 256;
        for (; i < total4; i += stride) {
            int k = i, si = 0;
            while (k >= segs.s[si].n4) { k -= segs.s[si].n4; ++si; }
            float4 v = ((const float4*)segs.s[si].src)[k];
            ushort4 h, l; cvt4(v, h, l);
            ((ushort4*)segs.s[si].hi)[k] = h;
            ((ushort4*)segs.s[si].lo)[k] = l;
        }
    }
}

// 4096-entry exclusive scan; also invdeg and cursor zeroing
__global__ __launch_bounds__(1024) void scan_kernel(
    const int* __restrict__ hist, int* __restrict__ row_ptr,
    float* __restrict__ invdeg, int* __restrict__ cursor, int E)
{
    __shared__ int s[1024];
    const int t = threadIdx.x;
    int4 c = reinterpret_cast<const int4*>(hist)[t];
    int local = c.x + c.y + c.z + c.w;
    s[t] = local;
    __syncthreads();
    for (int off = 1; off < 1024; off <<= 1) {
        int v = (t >= off) ? s[t - off] : 0;
        __syncthreads();
        s[t] += v;
        __syncthreads();
    }
    int base = s[t] - local;
    row_ptr[4 * t + 0] = base;
    row_ptr[4 * t + 1] = base + c.x;
    row_ptr[4 * t + 2] = base + c.x + c.y;
    row_ptr[4 * t + 3] = base + c.x + c.y + c.z;
    if (t == 1023) row_ptr[4096] = E;
    invdeg[4 * t + 0] = 1.0f / fmaxf((float)c.x, 1.0f);
    invdeg[4 * t + 1] = 1.0f / fmaxf((float)c.y, 1.0f);
    invdeg[4 * t + 2] = 1.0f / fmaxf((float)c.z, 1.0f);
    invdeg[4 * t + 3] = 1.0f / fmaxf((float)c.w, 1.0f);
    reinterpret_cast<int4*>(cursor)[t] = make_int4(0, 0, 0, 0);
}

__global__ void scatter_kernel(
    const int* __restrict__ src, const int* __restrict__ dst,
    const int* __restrict__ row_ptr, int* __restrict__ cursor,
    int* __restrict__ csr, int E)
{
    int e = blockIdx.x * blockDim.x + threadIdx.x;
    if (e >= E) return;
    int d = dst[e];
    int pos = atomicAdd(&cursor[d], 1);
    csr[row_ptr[d] + pos] = src[e];
}

__device__ __forceinline__ void add4(float4& a, const float4 b) {
    a.x += b.x; a.y += b.y; a.z += b.z; a.w += b.w;
}

// one wave per node: mean of neighbor rows -> bf16 hi/lo planes
__global__ __launch_bounds__(256) void node_agg(
    const int* __restrict__ row_ptr, const int* __restrict__ csr,
    const float* __restrict__ invdeg,
    const float* __restrict__ x, u16* __restrict__ agh, u16* __restrict__ agl, int D)
{
    const int wave = threadIdx.x >> 6;
    const int lane = threadIdx.x & 63;
    const int node = blockIdx.x * 4 + wave;
    const int beg = row_ptr[node], end = row_ptr[node + 1];
    const bool act = lane < (D >> 2);
    const int fo = lane * 4;

    float4 s0 = {0,0,0,0}, s1 = {0,0,0,0}, s2 = {0,0,0,0}, s3 = {0,0,0,0};
    int j = beg;
    for (; j + 3 < end; j += 4) {
        int n0 = csr[j], n1 = csr[j + 1], n2 = csr[j + 2], n3 = csr[j + 3];
        if (act) {
            add4(s0, *(const float4*)(&x[(size_t)n0 * D + fo]));
            add4(s1, *(const float4*)(&x[(size_t)n1 * D + fo]));
            add4(s2, *(const float4*)(&x[(size_t)n2 * D + fo]));
            add4(s3, *(const float4*)(&x[(size_t)n3 * D + fo]));
        }
    }
    for (; j < end; ++j) {
        int n = csr[j];
        if (act) add4(s0, *(const float4*)(&x[(size_t)n * D + fo]));
    }
    if (act) {
        const float inv = invdeg[node];
        float4 r;
        r.x = (s0.x + s1.x + s2.x + s3.x) * inv;
        r.y = (s0.y + s1.y + s2.y + s3.y) * inv;
        r.z = (s0.z + s1.z + s2.z + s3.z) * inv;
        r.w = (s0.w + s1.w + s2.w + s3.w) * inv;
        ushort4 h, l; cvt4(r, h, l);
        *(ushort4*)(&agh[(size_t)node * D + fo]) = h;
        *(ushort4*)(&agl[(size_t)node * D + fo]) = l;
    }
}

extern "C" void kernel_launch(void* const* d_in, const int* in_sizes, int n_in,
                              void* d_out, int out_size, void* d_ws, size_t ws_size,
                              hipStream_t stream)
{
    const float* P_weight     = (const float*)d_in[0];
    const float* model_proj_W = (const float*)d_in[1];
    const float* model_proj_b = (const float*)d_in[2];
    const float* sage1_Wl     = (const float*)d_in[3];
    const float* sage1_bl     = (const float*)d_in[4];
    const float* sage1_Wr     = (const float*)d_in[5];
    const float* sage2_Wl     = (const float*)d_in[6];
    const float* sage2_bl     = (const float*)d_in[7];
    const float* sage2_Wr     = (const float*)d_in[8];
    const float* Q_weight     = (const float*)d_in[9];
    const float* text_proj_W  = (const float*)d_in[10];
    const float* text_proj_b  = (const float*)d_in[11];
    const float* cls_W        = (const float*)d_in[12];
    const float* cls_b        = (const float*)d_in[13];
    const int*   edge_index   = (const int*)d_in[14];
    const int*   model_ids    = (const int*)d_in[15];
    const int*   prompt_ids   = (const int*)d_in[16];

    const int E = in_sizes[14] / 2;
    const int B = in_sizes[15];
    const int* srcE = edge_index;
    const int* dstE = edge_index + E;

    // ---- workspace layout ----
    const size_t nX0 = (size_t)NTRAIN * D0;
    const size_t nH1 = (size_t)NTRAIN * HID;
    const size_t nWp = (size_t)D0 * MED;
    const size_t nWs = (size_t)HID * D0;
    const size_t nWt = (size_t)D0 * TDIM;
    const size_t nWAll = nWp + 4 * nWs + nWt;

    float* fp  = (float*)d_ws;
    float* x0f = fp;  fp += nX0;
    float* h1f = fp;  fp += nH1;
    float* x2f = fp;  fp += nX0;
    u16* sp  = (u16*)fp;
    u16* x0h = sp;    sp += nX0;
    u16* x0l = sp;    sp += nX0;
    u16* h1h = sp;    sp += nH1;
    u16* h1l = sp;    sp += nH1;
    u16* agh = sp;    sp += nH1;      // max(D0,HID) rows
    u16* agl = sp;    sp += nH1;
    u16* Wh  = sp;    sp += nWAll;
    u16* Wl  = sp;    sp += nWAll;
    int* ib  = (int*)sp;
    int*   hist    = ib;               // 4096
    int*   cursor  = ib + 4096;        // 4096
    int*   row_ptr = ib + 8192;        // 4097 (padded)
    float* invdeg  = (float*)(ib + 12304);
    int*   csr     = ib + 16400;

    u16 *Wph = Wh,            *Wpl = Wl;
    u16 *W1lh = Wh + nWp,     *W1ll = Wl + nWp;
    u16 *W1rh = W1lh + nWs,   *W1rl = W1ll + nWs;
    u16 *W2lh = W1rh + nWs,   *W2ll = W1rl + nWs;
    u16 *W2rh = W2lh + nWs,   *W2rl = W2ll + nWs;
    u16 *Wth  = W2rh + nWs,   *Wtl  = W2rl + nWs;

    dim3 blk(256);

    // zero hist only (cursor zeroed by scan_kernel)
    hipMemsetAsync(hist, 0, 4096 * sizeof(int), stream);

    // fused: edge histogram + weight hi/lo plane conversion
    Segs segs;
    segs.s[0] = {model_proj_W, Wph,  Wpl,  (int)(nWp / 4)};
    segs.s[1] = {sage1_Wl,     W1lh, W1ll, (int)(nWs / 4)};
    segs.s[2] = {sage1_Wr,     W1rh, W1rl, (int)(nWs / 4)};
    segs.s[3] = {sage2_Wl,     W2lh, W2ll, (int)(nWs / 4)};
    segs.s[4] = {sage2_Wr,     W2rh, W2rl, (int)(nWs / 4)};
    segs.s[5] = {text_proj_W,  Wth,  Wtl,  (int)(nWt / 4)};
    const int HB = (E + 255) / 256;
    hist_conv<<<HB + 512, blk, 0, stream>>>(dstE, hist, E, HB, segs, (int)(nWAll / 4));

    scan_kernel<<<1, 1024, 0, stream>>>(hist, row_ptr, invdeg, cursor, E);
    scatter_kernel<<<(E + 255) / 256, blk, 0, stream>>>(srcE, dstE, row_ptr, cursor, csr, E);

    // x0 = P[:4096] @ Wp^T + b   (fp32 A, converts in staging; emits planes)
    gemm_node<1, 0, 1, 1><<<dim3(4, NTRAIN / 32), blk, 0, stream>>>(
        P_weight, nullptr, nullptr,
        (const short*)Wph, (const short*)Wpl,
        nullptr, nullptr, nullptr, nullptr,
        model_proj_b, x0f, x0h, x0l, NTRAIN, D0, MED);

    // layer-1 aggregation -> planes
    node_agg<<<NTRAIN / 4, blk, 0, stream>>>(row_ptr, csr, invdeg, x0f, agh, agl, D0);

    // h1 = relu(agg @ W1l^T + b1 + x0 @ W1r^T)   (all pre-split; emits planes)
    gemm_node<0, 1, 1, 2><<<dim3(4, NTRAIN / 32), blk, 0, stream>>>(
        nullptr, (const short*)agh, (const short*)agl,
        (const short*)W1lh, (const short*)W1ll,
        (const short*)x0h, (const short*)x0l,
        (const short*)W1rh, (const short*)W1rl,
        sage1_bl, h1f, h1h, h1l, NTRAIN, HID, D0);

    // layer-2 aggregation -> planes
    node_agg<<<NTRAIN / 4, blk, 0, stream>>>(row_ptr, csr, invdeg, h1f, agh, agl, HID);

    // x2 = agg @ W2l^T + b2 + h1 @ W2r^T
    gemm_node<0, 0, 0, 2><<<dim3(4, NTRAIN / 32), blk, 0, stream>>>(
        nullptr, (const short*)agh, (const short*)agl,
        (const short*)W2lh, (const short*)W2ll,
        (const short*)h1h, (const short*)h1l,
        (const short*)W2rh, (const short*)W2rl,
        sage2_bl, x2f, nullptr, nullptr, NTRAIN, D0, HID);

    // fused q-GEMM + head -> d_out
    gemm_q_head<<<B / 64, blk, 0, stream>>>(
        Q_weight, prompt_ids, (const short*)Wth, (const short*)Wtl,
        text_proj_b, x2f, model_ids, cls_W, cls_b, (float*)d_out);
}